// Round 11
// baseline (237.955 us; speedup 1.0000x reference)
//
#include <hip/hip_runtime.h>

#define NN 100000
#define NE 600000
#define DIN 128
#define DOUT 64
#define SCAN_B 512
#define NBLK ((NN + SCAN_B - 1) / SCAN_B)  // 196
#define HIST_B ((NE + 255) / 256)          // 2344
#define PREP_N (DIN * DIN + DIN * DOUT)    // 24576
#define PREP_B ((PREP_N + 255) / 256)      // 96

typedef __attribute__((ext_vector_type(8))) short bf16x8;
typedef __attribute__((ext_vector_type(4))) short s16x4;
typedef __attribute__((ext_vector_type(4))) float f32x4;
typedef __attribute__((ext_vector_type(2))) float f32x2;

__device__ inline short f2bf(float f) {  // RTN-even fp32 -> bf16 bits
  union { float f; unsigned u; } v; v.f = f;
  unsigned r = (v.u + 0x7FFF + ((v.u >> 16) & 1)) >> 16;
  return (short)r;
}
__device__ inline float bf2f(unsigned short u) {
  union { unsigned u; float f; } v; v.u = ((unsigned)u) << 16;
  return v.f;
}
// pack 4 f32 -> 4 fp8 e4m3 bytes (one dword)
__device__ inline unsigned pk4_fp8(float a, float b, float c, float d) {
  unsigned lo = __builtin_amdgcn_cvt_pk_fp8_f32(a, b, 0, false);
  return __builtin_amdgcn_cvt_pk_fp8_f32(c, d, lo, true);
}
// 16 fp8 bytes -> 16 f32 FMAs into acc[]
__device__ inline void fma_fp8x16(uint4 q, float w, float* acc) {
  f32x2 f;
  f = __builtin_amdgcn_cvt_pk_f32_fp8(q.x, false); acc[0] += w * f[0];  acc[1] += w * f[1];
  f = __builtin_amdgcn_cvt_pk_f32_fp8(q.x, true);  acc[2] += w * f[0];  acc[3] += w * f[1];
  f = __builtin_amdgcn_cvt_pk_f32_fp8(q.y, false); acc[4] += w * f[0];  acc[5] += w * f[1];
  f = __builtin_amdgcn_cvt_pk_f32_fp8(q.y, true);  acc[6] += w * f[0];  acc[7] += w * f[1];
  f = __builtin_amdgcn_cvt_pk_f32_fp8(q.z, false); acc[8] += w * f[0];  acc[9] += w * f[1];
  f = __builtin_amdgcn_cvt_pk_f32_fp8(q.z, true);  acc[10] += w * f[0]; acc[11] += w * f[1];
  f = __builtin_amdgcn_cvt_pk_f32_fp8(q.w, false); acc[12] += w * f[0]; acc[13] += w * f[1];
  f = __builtin_amdgcn_cvt_pk_f32_fp8(q.w, true);  acc[14] += w * f[0]; acc[15] += w * f[1];
}

// ------- hist (+ rank capture + fused W1^T / W2^T bf16 prep) ----------------
__global__ __launch_bounds__(256) void hist_prep_kernel(const int* __restrict__ ei,
                                                        int* __restrict__ cnt,
                                                        int* __restrict__ rank,
                                                        const float* __restrict__ W1,
                                                        short* __restrict__ w1t,
                                                        const float* __restrict__ W2,
                                                        short* __restrict__ w2t) {
  const int b = blockIdx.x, t = threadIdx.x;
  if (b < HIST_B) {
    int e = b * 256 + t;
    if (e < NE) rank[e] = atomicAdd(&cnt[ei[NE + e]], 1);  // rank = old count
  } else {
    int i = (b - HIST_B) * 256 + t;
    if (i < DIN * DIN) {
      int n = i >> 7, k = i & 127;
      w1t[i] = f2bf(W1[k * DIN + n]);            // w1t[n][k]
    } else if (i < PREP_N) {
      int i2 = i - DIN * DIN;
      int n = i2 >> 7, k = i2 & 127;
      w2t[i2] = f2bf(W2[k * DOUT + n]);          // w2t[n][k]
    }
  }
}

__global__ __launch_bounds__(512) void scan_local_kernel(const int* __restrict__ cnt,
                                                         int* __restrict__ row_ptr,
                                                         int* __restrict__ blk_sum) {
  __shared__ int s[512];
  const int b = blockIdx.x, t = threadIdx.x;
  const int i = b * 512 + t;
  int v = (i < NN) ? cnt[i] : 0;
  s[t] = v;
  __syncthreads();
  for (int off = 1; off < 512; off <<= 1) {
    int u = (t >= off) ? s[t - off] : 0;
    __syncthreads();
    s[t] += u;
    __syncthreads();
  }
  if (i < NN) row_ptr[i] = s[t] - v;  // block-local exclusive
  if (t == 511) blk_sum[b] = s[511];
}

// each block redundantly scans the 196 block sums in LDS, adds its offset
__global__ __launch_bounds__(512) void scan_add_kernel(int* __restrict__ row_ptr,
                                                       const int* __restrict__ blk_sum) {
  __shared__ int s[512];
  const int b = blockIdx.x, t = threadIdx.x;
  s[t] = (t < NBLK) ? blk_sum[t] : 0;
  __syncthreads();
  for (int off = 1; off < 512; off <<= 1) {
    int u = (t >= off) ? s[t - off] : 0;
    __syncthreads();
    s[t] += u;
    __syncthreads();
  }
  int off = (b > 0) ? s[b - 1] : 0;
  const int i = b * 512 + t;
  if (i < NN) row_ptr[i] += off;
  if (b == 0 && t == 0) row_ptr[NN] = NE;
}

// atomic-free scatter: pos = row_ptr[dst] + rank[e]
__global__ __launch_bounds__(256) void scatter_kernel(const int* __restrict__ ei,
                                                      const float* __restrict__ ew,
                                                      const int* __restrict__ row_ptr,
                                                      const int* __restrict__ rank,
                                                      int2* __restrict__ ep) {
  int e = blockIdx.x * 256 + threadIdx.x;
  if (e >= NE) return;
  int src = ei[e];
  int dst = ei[NE + e];
  int pos = row_ptr[dst] + rank[e];
  ep[pos] = make_int2(src, __float_as_int(ew[e]));
}

// ---------------- GEMM1 via MFMA bf16: h0(fp8 e4m3) = x @ W1 ----------------
// OPERAND-SWAPPED: mfma(A=w_frag, B=x_frag) computes D^T, so lane&15 indexes
// the h0 ROW and quad*4+reg indexes 4 CONSECUTIVE h0 columns -> packed 4B
// stores (16/thread) instead of 64 byte-stores.
#define G1_BM 128
#define XS_PITCH 136
__global__ __launch_bounds__(256) void gemm1_mfma_kernel(const float* __restrict__ x,
                                                         const short* __restrict__ w1t,
                                                         unsigned char* __restrict__ h0) {
  __shared__ short xs[G1_BM][XS_PITCH];
  const int t = threadIdx.x;
  const int row0 = blockIdx.x * G1_BM;
#pragma unroll
  for (int i = 0; i < 16; ++i) {
    int f = t + i * 256;
    int r = f >> 5, c4 = f & 31;
    int gr = row0 + r;
    float4 v = (gr < NN) ? *(const float4*)&x[(size_t)gr * DIN + c4 * 4]
                         : make_float4(0.f, 0.f, 0.f, 0.f);
    s16x4 s;
    s.x = f2bf(v.x); s.y = f2bf(v.y); s.z = f2bf(v.z); s.w = f2bf(v.w);
    *(s16x4*)&xs[r][c4 * 4] = s;
  }
  __syncthreads();

  const int wave = t >> 6, lane = t & 63;
  const int nlane = lane & 15, quad = lane >> 4;
  const int mbase = wave * 32;
  f32x4 acc[2][8];
#pragma unroll
  for (int mt = 0; mt < 2; ++mt)
#pragma unroll
    for (int nt = 0; nt < 8; ++nt) acc[mt][nt] = (f32x4){0.f, 0.f, 0.f, 0.f};

#pragma unroll
  for (int ks = 0; ks < 4; ++ks) {
    const int koff = ks * 32 + quad * 8;
    bf16x8 a0 = *(const bf16x8*)&xs[mbase + nlane][koff];
    bf16x8 a1 = *(const bf16x8*)&xs[mbase + 16 + nlane][koff];
#pragma unroll
    for (int nt = 0; nt < 8; ++nt) {
      bf16x8 b = *(const bf16x8*)&w1t[(size_t)(nt * 16 + nlane) * DIN + koff];
      // swapped: D^T
      acc[0][nt] = __builtin_amdgcn_mfma_f32_16x16x32_bf16(b, a0, acc[0][nt], 0, 0, 0);
      acc[1][nt] = __builtin_amdgcn_mfma_f32_16x16x32_bf16(b, a1, acc[1][nt], 0, 0, 0);
    }
  }

#pragma unroll
  for (int mt = 0; mt < 2; ++mt) {
    int gr = row0 + mbase + mt * 16 + nlane;  // h0 row owned by this lane
    if (gr < NN) {
#pragma unroll
      for (int nt = 0; nt < 8; ++nt) {
        unsigned pk = pk4_fp8(acc[mt][nt][0], acc[mt][nt][1], acc[mt][nt][2], acc[mt][nt][3]);
        *(unsigned*)&h0[(size_t)gr * DIN + nt * 16 + quad * 4] = pk;
      }
    }
  }
}

// -------- GEMM2 via MFMA bf16: h2(bf16) = relu(acc1(bf16) + b1) @ W2 --------
// Same operand-swap: lane owns 4 consecutive h2 columns -> 8B stores.
__global__ __launch_bounds__(256) void gemm2_mfma_kernel(const short* __restrict__ acc1,
                                                         const float* __restrict__ b1,
                                                         const short* __restrict__ w2t,
                                                         short* __restrict__ h2) {
  __shared__ short xs[G1_BM][XS_PITCH];
  const int t = threadIdx.x;
  const int row0 = blockIdx.x * G1_BM;
#pragma unroll
  for (int i = 0; i < 8; ++i) {
    int f = t + i * 256;
    int r = f >> 4, c8 = f & 15;
    int gr = row0 + r;
    bf16x8 v = (gr < NN) ? *(const bf16x8*)&acc1[(size_t)gr * DIN + c8 * 8]
                         : (bf16x8){0, 0, 0, 0, 0, 0, 0, 0};
    bf16x8 s;
#pragma unroll
    for (int j = 0; j < 8; ++j) {
      float fv = bf2f((unsigned short)v[j]) + b1[c8 * 8 + j];
      s[j] = f2bf(fmaxf(fv, 0.f));
    }
    *(bf16x8*)&xs[r][c8 * 8] = s;
  }
  __syncthreads();

  const int wave = t >> 6, lane = t & 63;
  const int nlane = lane & 15, quad = lane >> 4;
  const int mbase = wave * 32;
  f32x4 acc[2][4];
#pragma unroll
  for (int mt = 0; mt < 2; ++mt)
#pragma unroll
    for (int nt = 0; nt < 4; ++nt) acc[mt][nt] = (f32x4){0.f, 0.f, 0.f, 0.f};

#pragma unroll
  for (int ks = 0; ks < 4; ++ks) {
    const int koff = ks * 32 + quad * 8;
    bf16x8 a0 = *(const bf16x8*)&xs[mbase + nlane][koff];
    bf16x8 a1 = *(const bf16x8*)&xs[mbase + 16 + nlane][koff];
#pragma unroll
    for (int nt = 0; nt < 4; ++nt) {
      bf16x8 b = *(const bf16x8*)&w2t[(size_t)(nt * 16 + nlane) * DIN + koff];
      acc[0][nt] = __builtin_amdgcn_mfma_f32_16x16x32_bf16(b, a0, acc[0][nt], 0, 0, 0);
      acc[1][nt] = __builtin_amdgcn_mfma_f32_16x16x32_bf16(b, a1, acc[1][nt], 0, 0, 0);
    }
  }

#pragma unroll
  for (int mt = 0; mt < 2; ++mt) {
    int gr = row0 + mbase + mt * 16 + nlane;  // h2 row owned by this lane
    if (gr < NN) {
#pragma unroll
      for (int nt = 0; nt < 4; ++nt) {
        s16x4 s;
        s.x = f2bf(acc[mt][nt][0]);
        s.y = f2bf(acc[mt][nt][1]);
        s.z = f2bf(acc[mt][nt][2]);
        s.w = f2bf(acc[mt][nt][3]);
        *(s16x4*)&h2[(size_t)gr * DOUT + nt * 16 + quad * 4] = s;
      }
    }
  }
}

// ------- spmm1: acc1(bf16) = A @ h0(fp8), LPE=8, lane owns 16 elems ---------
__global__ __launch_bounds__(256) void spmm1_fp8_kernel(const int* __restrict__ rp,
                                                        const int2* __restrict__ ep,
                                                        const unsigned char* __restrict__ h,
                                                        short* __restrict__ acc1) {
  const int row = blockIdx.x * 32 + (threadIdx.x >> 3);
  const int lane = threadIdx.x & 7;  // owns bytes [lane*16, lane*16+16)
  if (row >= NN) return;
  const int b = rp[row], e = rp[row + 1];
  float acc[16];
#pragma unroll
  for (int j = 0; j < 16; ++j) acc[j] = 0.f;
  int i = b;
  for (; i + 4 <= e; i += 4) {
    int2 p0 = ep[i], p1 = ep[i + 1], p2 = ep[i + 2], p3 = ep[i + 3];
    uint4 q0 = *(const uint4*)&h[(size_t)p0.x * DIN + lane * 16];
    uint4 q1 = *(const uint4*)&h[(size_t)p1.x * DIN + lane * 16];
    uint4 q2 = *(const uint4*)&h[(size_t)p2.x * DIN + lane * 16];
    uint4 q3 = *(const uint4*)&h[(size_t)p3.x * DIN + lane * 16];
    fma_fp8x16(q0, __int_as_float(p0.y), acc);
    fma_fp8x16(q1, __int_as_float(p1.y), acc);
    fma_fp8x16(q2, __int_as_float(p2.y), acc);
    fma_fp8x16(q3, __int_as_float(p3.y), acc);
  }
  if (i + 2 <= e) {
    int2 p0 = ep[i], p1 = ep[i + 1];
    uint4 q0 = *(const uint4*)&h[(size_t)p0.x * DIN + lane * 16];
    uint4 q1 = *(const uint4*)&h[(size_t)p1.x * DIN + lane * 16];
    fma_fp8x16(q0, __int_as_float(p0.y), acc);
    fma_fp8x16(q1, __int_as_float(p1.y), acc);
    i += 2;
  }
  if (i < e) {
    int2 p0 = ep[i];
    uint4 q0 = *(const uint4*)&h[(size_t)p0.x * DIN + lane * 16];
    fma_fp8x16(q0, __int_as_float(p0.y), acc);
  }
  bf16x8 o0, o1;
#pragma unroll
  for (int j = 0; j < 8; ++j) { o0[j] = f2bf(acc[j]); o1[j] = f2bf(acc[8 + j]); }
  *(bf16x8*)&acc1[(size_t)row * DIN + lane * 16] = o0;
  *(bf16x8*)&acc1[(size_t)row * DIN + lane * 16 + 8] = o1;
}

// ------- spmm2: out(fp32) = A @ h2(bf16) + b2, LPE=8, lane owns 8 elems -----
__global__ __launch_bounds__(256) void spmm2_kernel(const int* __restrict__ rp,
                                                    const int2* __restrict__ ep,
                                                    const short* __restrict__ h,
                                                    const float* __restrict__ bias,
                                                    float* __restrict__ out) {
  const int row = blockIdx.x * 32 + (threadIdx.x >> 3);
  const int lane = threadIdx.x & 7;  // owns elems [lane*8, lane*8+8)
  if (row >= NN) return;
  const int b = rp[row], e = rp[row + 1];
  float acc[8];
#pragma unroll
  for (int j = 0; j < 8; ++j) acc[j] = 0.f;
  int i = b;
  for (; i + 4 <= e; i += 4) {
    int2 p0 = ep[i], p1 = ep[i + 1], p2 = ep[i + 2], p3 = ep[i + 3];
    bf16x8 v0 = *(const bf16x8*)&h[(size_t)p0.x * DOUT + lane * 8];
    bf16x8 v1 = *(const bf16x8*)&h[(size_t)p1.x * DOUT + lane * 8];
    bf16x8 v2 = *(const bf16x8*)&h[(size_t)p2.x * DOUT + lane * 8];
    bf16x8 v3 = *(const bf16x8*)&h[(size_t)p3.x * DOUT + lane * 8];
    float w0 = __int_as_float(p0.y), w1 = __int_as_float(p1.y);
    float w2 = __int_as_float(p2.y), w3 = __int_as_float(p3.y);
#pragma unroll
    for (int j = 0; j < 8; ++j)
      acc[j] += w0 * bf2f((unsigned short)v0[j]) + w1 * bf2f((unsigned short)v1[j]) +
                w2 * bf2f((unsigned short)v2[j]) + w3 * bf2f((unsigned short)v3[j]);
  }
  if (i + 2 <= e) {
    int2 p0 = ep[i], p1 = ep[i + 1];
    bf16x8 v0 = *(const bf16x8*)&h[(size_t)p0.x * DOUT + lane * 8];
    bf16x8 v1 = *(const bf16x8*)&h[(size_t)p1.x * DOUT + lane * 8];
    float w0 = __int_as_float(p0.y), w1 = __int_as_float(p1.y);
#pragma unroll
    for (int j = 0; j < 8; ++j)
      acc[j] += w0 * bf2f((unsigned short)v0[j]) + w1 * bf2f((unsigned short)v1[j]);
    i += 2;
  }
  if (i < e) {
    int2 p0 = ep[i];
    bf16x8 v0 = *(const bf16x8*)&h[(size_t)p0.x * DOUT + lane * 8];
    float w0 = __int_as_float(p0.y);
#pragma unroll
    for (int j = 0; j < 8; ++j) acc[j] += w0 * bf2f((unsigned short)v0[j]);
  }
#pragma unroll
  for (int j = 0; j < 8; ++j) acc[j] += bias[lane * 8 + j];
  *(float4*)&out[(size_t)row * DOUT + lane * 8] = make_float4(acc[0], acc[1], acc[2], acc[3]);
  *(float4*)&out[(size_t)row * DOUT + lane * 8 + 4] = make_float4(acc[4], acc[5], acc[6], acc[7]);
}

extern "C" void kernel_launch(void* const* d_in, const int* in_sizes, int n_in,
                              void* d_out, int out_size, void* d_ws, size_t ws_size,
                              hipStream_t stream) {
  const float* x  = (const float*)d_in[0];
  const int*   ei = (const int*)d_in[1];
  const float* ew = (const float*)d_in[2];
  const float* W1 = (const float*)d_in[3];
  const float* b1 = (const float*)d_in[4];
  const float* W2 = (const float*)d_in[5];
  const float* b2 = (const float*)d_in[6];
  float* out = (float*)d_out;

  // workspace layout — ~46.5 MB (82.4 MB proven safe)
  char* p = (char*)d_ws;
  int*   cnt     = (int*)p;                 p += sizeof(int) * NN;
  int*   row_ptr = (int*)p;                 p += sizeof(int) * (NN + 4);
  int*   blk_sum = (int*)p;                 p += sizeof(int) * (NBLK + 4);
  int*   rank    = (int*)p;                 p += sizeof(int) * NE;
  int2*  ep      = (int2*)p;                p += sizeof(int2) * NE;      // (src, w)
  short* w1t     = (short*)p;               p += sizeof(short) * DIN * DIN;
  short* w2t     = (short*)p;               p += sizeof(short) * DIN * DOUT;
  unsigned char* h0 = (unsigned char*)p;    p += (size_t)NN * DIN;      // fp8 e4m3
  short* acc1    = (short*)p;               // [NN, DIN] bf16
  short* h2      = (short*)h0;              // h0 dead after spmm1; [NN, DOUT] bf16

  // CSR build + weight prep
  hipMemsetAsync(cnt, 0, sizeof(int) * NN, stream);
  hist_prep_kernel<<<HIST_B + PREP_B, 256, 0, stream>>>(ei, cnt, rank, W1, w1t, W2, w2t);
  scan_local_kernel<<<NBLK, 512, 0, stream>>>(cnt, row_ptr, blk_sum);
  scan_add_kernel<<<NBLK, 512, 0, stream>>>(row_ptr, blk_sum);
  scatter_kernel<<<HIST_B, 256, 0, stream>>>(ei, ew, row_ptr, rank, ep);

  // layer 1
  gemm1_mfma_kernel<<<(NN + G1_BM - 1) / G1_BM, 256, 0, stream>>>(x, w1t, h0);
  spmm1_fp8_kernel<<<(NN + 31) / 32, 256, 0, stream>>>(row_ptr, ep, h0, acc1);

  // layer 2
  gemm2_mfma_kernel<<<(NN + G1_BM - 1) / G1_BM, 256, 0, stream>>>(acc1, b1, w2t, h2);
  spmm2_kernel<<<(NN + 31) / 32, 256, 0, stream>>>(row_ptr, ep, h2, b2, out);
}